// Round 4
// baseline (200.073 us; speedup 1.0000x reference)
//
#include <hip/hip_runtime.h>

#define BATCH 16
#define CH    64
#define TLEN  200
#define NP    30
#define HID   128
#define NSEQ  (BATCH * NP)   // 480
#define HXP   136            // h row pitch in halves (272 B)
#define XBP   72             // x-tile row pitch in halves

typedef _Float16 half8  __attribute__((ext_vector_type(8)));
typedef _Float16 half4v __attribute__((ext_vector_type(4)));
typedef float    f32x4  __attribute__((ext_vector_type(4)));

__device__ __forceinline__ float sigm_fast(float x) {
    return __builtin_amdgcn_rcpf(1.0f + __expf(-x));
}
__device__ __forceinline__ float tanh_fast(float x) {
    float xc = fminf(15.0f, fmaxf(-15.0f, x));
    float e = __expf(2.0f * xc);
    return (e - 1.0f) * __builtin_amdgcn_rcpf(e + 1.0f);
}
__device__ __forceinline__ half8 cvt8(float4 a, float4 b) {
    return (half8){(_Float16)a.x,(_Float16)a.y,(_Float16)a.z,(_Float16)a.w,
                   (_Float16)b.x,(_Float16)b.y,(_Float16)b.z,(_Float16)b.w};
}

#define MFMA16(A,B,C) __builtin_amdgcn_mfma_f32_16x16x32_f16((A),(B),(C),0,0,0)

// ---------------------------------------------------------------------------
// Fused LSTM. 240 blocks (XCD-swizzled), 256 threads = 4 waves = 1 wave/SIMD.
// Wave w owns hid [32w, 32w+32) = 2 N-tiles per gate type -> 32 MFMAs/wave/step
// (same 620 cyc/SIMD MFMA floor as 8-wave, but act/barrier/LDS cost halves).
//   - h replicated to rows {8s, 8s+4}: C reg 0 (row 4*lq) IS this lane's seq,
//     so act = full 64 lanes, 1 cell/lane, 1 cndmask/gate (ct-tile select).
//   - xg precomputed per 8-step period via one 16-MFMA burst at k==0.
//   - x staged 2 periods ahead by threads 0..127 (1 load + 1 LDS write/step).
// ---------------------------------------------------------------------------
__global__ __launch_bounds__(256, 1) void fused_lstm(
    const float* __restrict__ x, const float* __restrict__ W_ih,
    const float* __restrict__ W_hh, const float* __restrict__ b_ih,
    const float* __restrict__ b_hh, const float* __restrict__ W_fc,
    const float* __restrict__ b_fc, float* __restrict__ out)
{
    const int tid = threadIdx.x;
    const int w  = tid >> 6;     // wave 0..3 -> owns hid [32w,32w+32)
    const int l  = tid & 63;
    const int lr = l & 15;
    const int lq = l >> 4;

    // XCD-chunked swizzle: XCD c gets pairs c*30..c*30+29 (= 2 full batches)
    const int blk  = blockIdx.x;
    const int pair = (blk & 7) * 30 + (blk >> 3);
    const int n0 = pair * 2;
    const int b0 = n0 / NP;
    const int p0 = n0 % NP;      // even -> both seqs share b0

    __shared__ __align__(16) _Float16 hx2[2][16][HXP];   // h: rows {0,4}=s0, {8,12}=s1, rest 0
    __shared__ __align__(16) _Float16 xbuf[2][16][XBP];  // x tiles, row = 2*delta + s
    __shared__ __align__(16) _Float16 xgb[2][8][HID][8]; // xg+bias: [buf][delta][hid][s*4+{i,f,g,o}]

    // ---- W fragments in registers (loaded once) ----
    half8 bhh[4][2][4];   // [gate T][col-tile ct][K-frag]  (K=128)
    half8 bih[4][2][2];   // [T][ct][K-frag]                (K=64)
    float biasx[4][2];
#pragma unroll
    for (int T = 0; T < 4; ++T)
#pragma unroll
      for (int ct = 0; ct < 2; ++ct) {
        const int g = 128*T + 32*w + 16*ct + lr;
        const float* rh = W_hh + (size_t)g * HID;
        const float* ri = W_ih + (size_t)g * CH;
#pragma unroll
        for (int kt = 0; kt < 4; ++kt) {
            const int k0 = 32*kt + 8*lq;
            bhh[T][ct][kt] = cvt8(*(const float4*)(rh + k0), *(const float4*)(rh + k0 + 4));
        }
#pragma unroll
        for (int j = 0; j < 2; ++j) {
            const int k0 = 32*j + 8*lq;
            bih[T][ct][j] = cvt8(*(const float4*)(ri + k0), *(const float4*)(ri + k0 + 4));
        }
        biasx[T][ct] = b_ih[g] + b_hh[g];
      }

    // zero hx2 (unused rows stay zero forever; live rows init h_0 = 0)
    for (int i = tid; i < (2*16*HXP)/2; i += 256) ((unsigned*)hx2)[i] = 0u;

    // ---- x loaders: threads 0..127, one (s,ch) each
    const bool isload = (tid < 128);
    int ls = 0, lc = 0;
    const float* xbase = nullptr;
    float xpend = 0.f;
    if (isload) {
        ls = tid >> 6;                    // seq 0/1
        lc = tid & 63;                    // channel
        xbase = x + ((size_t)(b0 * CH + lc) * TLEN) * NP + p0 + ls;
#pragma unroll
        for (int u = 0; u < 16; ++u)      // prologue: periods 0 and 1
            xbuf[u >> 3][2*(u & 7) + ls][lc] = (_Float16)xbase[(size_t)u * NP];
        xpend = xbase[(size_t)16 * NP];   // preload t=16 (staged at t=0)
    }
    float cst = 0.f;                      // c-state: every thread owns 1 cell
    const int hcell = 32*w + (l & 31);    // this thread's hid
    const int sb    = l >> 5;             // this thread's seq
    const int ctb   = (l >> 4) & 1;       // which ct-tile holds this thread's col
    __syncthreads();

    // per-period xg GEMM: x-tile (16 rows = 8 steps x 2 seqs, K=64), bias folded.
    // C reg r of lane (lr,lq) = row 4lq+r -> delta = 2lq+(r>>1), s = r&1.
#define XG_BURST(SB, TB) {                                                        \
        const _Float16* xr_ = &xbuf[SB][lr][8*lq];                                \
        half8 xf0_ = *(const half8*)xr_;                                          \
        half8 xf1_ = *(const half8*)(xr_ + 32);                                   \
        f32x4 xg_[4][2];                                                          \
        _Pragma("unroll") for (int T_ = 0; T_ < 4; ++T_)                          \
        { _Pragma("unroll") for (int c_ = 0; c_ < 2; ++c_) {                      \
            f32x4 a_ = {biasx[T_][c_], biasx[T_][c_], biasx[T_][c_], biasx[T_][c_]}; \
            a_ = MFMA16(xf0_, bih[T_][c_][0], a_);                                \
            a_ = MFMA16(xf1_, bih[T_][c_][1], a_);                                \
            xg_[T_][c_] = a_;                                                     \
        } }                                                                       \
        _Pragma("unroll") for (int c_ = 0; c_ < 2; ++c_) {                        \
            const int hc_ = 32*w + 16*c_ + lr;                                    \
            half8 r01_ = {(_Float16)xg_[0][c_][0],(_Float16)xg_[1][c_][0],        \
                          (_Float16)xg_[2][c_][0],(_Float16)xg_[3][c_][0],        \
                          (_Float16)xg_[0][c_][1],(_Float16)xg_[1][c_][1],        \
                          (_Float16)xg_[2][c_][1],(_Float16)xg_[3][c_][1]};       \
            half8 r23_ = {(_Float16)xg_[0][c_][2],(_Float16)xg_[1][c_][2],        \
                          (_Float16)xg_[2][c_][2],(_Float16)xg_[3][c_][2],        \
                          (_Float16)xg_[0][c_][3],(_Float16)xg_[1][c_][3],        \
                          (_Float16)xg_[2][c_][3],(_Float16)xg_[3][c_][3]};       \
            *(half8*)&xgb[TB][2*lq][hc_][0]     = r01_;                           \
            *(half8*)&xgb[TB][2*lq + 1][hc_][0] = r23_;                           \
        } }

    XG_BURST(0, 0)          // xg for period 0
    __syncthreads();

#pragma unroll 1
    for (int p = 0; p < 25; ++p) {
        const int pe = p & 1;
#pragma unroll
        for (int k = 0; k < 8; ++k) {
            const int cur = k & 1;       // t = 8p+k, t&1 = k&1
            const int nxt = cur ^ 1;
            // xg prefetch (b64, conflict-free); latency hides under MFMA issue
            half4v xgv = *(const half4v*)&xgb[pe][k][hcell][4*sb];
            // A fragments (h, K=128); zero rows -> dead C rows
            const _Float16* hr = &hx2[cur][lr][8*lq];
            half8 a0 = *(const half8*)(hr);
            half8 a1 = *(const half8*)(hr + 32);
            half8 a2 = *(const half8*)(hr + 64);
            half8 a3 = *(const half8*)(hr + 96);
            f32x4 acc[4][2];
#pragma unroll
            for (int T = 0; T < 4; ++T)
#pragma unroll
              for (int c = 0; c < 2; ++c) {
                f32x4 z = {0.f, 0.f, 0.f, 0.f};
                z = MFMA16(a0, bhh[T][c][0], z);
                z = MFMA16(a1, bhh[T][c][1], z);
                z = MFMA16(a2, bhh[T][c][2], z);
                z = MFMA16(a3, bhh[T][c][3], z);
                acc[T][c] = z;
              }
            if (k == 0 && p < 24) XG_BURST(pe ^ 1, pe ^ 1)   // xg for period p+1
            if (isload) {
                // stage x for period p+2: t = 8p+k+16 -> row 2k+s of xbuf[pe]
                xbuf[pe][2*k + ls][lc] = (_Float16)xpend;
                int tq = 8*p + k + 17;
                tq = tq > TLEN - 1 ? TLEN - 1 : tq;
                xpend = xbase[(size_t)tq * NP];
            }
            {
                // reg 0 = C row 4*lq; rows {0,4}=s0, {8,12}=s1 -> reg 0 IS this
                // lane's seq. Only select left: ct-tile (1 cndmask/gate).
                float gi = (ctb ? acc[0][1][0] : acc[0][0][0]) + (float)xgv[0];
                float gf = (ctb ? acc[1][1][0] : acc[1][0][0]) + (float)xgv[1];
                float gg = (ctb ? acc[2][1][0] : acc[2][0][0]) + (float)xgv[2];
                float go = (ctb ? acc[3][1][0] : acc[3][0][0]) + (float)xgv[3];
                cst = sigm_fast(gf) * cst + sigm_fast(gi) * tanh_fast(gg);
                float hv = sigm_fast(go) * tanh_fast(cst);
                _Float16 hh = (_Float16)hv;
                hx2[nxt][8*sb][hcell]     = hh;   // primary replica row
                hx2[nxt][8*sb + 4][hcell] = hh;   // second replica row
            }
            __syncthreads();
        }
    }

    // FC epilogue: h_200 in hx2[0], seq s at row 8*s (t=199 wrote nxt=0)
    if (tid < 2 * CH) {
        const int s = tid >> 6, ch = tid & 63;
        const float* wf = W_fc + (size_t)ch * HID;
        float acc = b_fc[ch];
#pragma unroll
        for (int j8 = 0; j8 < 16; ++j8) {
            half8 hv = *(const half8*)&hx2[0][8*s][8 * j8];
            float4 w0 = *(const float4*)(wf + 8 * j8);
            float4 w1 = *(const float4*)(wf + 8 * j8 + 4);
            acc += w0.x * (float)hv[0] + w0.y * (float)hv[1]
                 + w0.z * (float)hv[2] + w0.w * (float)hv[3]
                 + w1.x * (float)hv[4] + w1.y * (float)hv[5]
                 + w1.z * (float)hv[6] + w1.w * (float)hv[7];
        }
        out[(size_t)(n0 + s) * CH + ch] = acc;
    }
}

extern "C" void kernel_launch(void* const* d_in, const int* in_sizes, int n_in,
                              void* d_out, int out_size, void* d_ws, size_t ws_size,
                              hipStream_t stream) {
    (void)in_sizes; (void)n_in; (void)out_size; (void)d_ws; (void)ws_size;
    fused_lstm<<<NSEQ / 2, 256, 0, stream>>>(
        (const float*)d_in[0], (const float*)d_in[1], (const float*)d_in[2],
        (const float*)d_in[3], (const float*)d_in[4], (const float*)d_in[5],
        (const float*)d_in[6], (float*)d_out);
}

// Round 5
// 195.638 us; speedup vs baseline: 1.0227x; 1.0227x over previous
//
#include <hip/hip_runtime.h>

#define BATCH 16
#define CH    64
#define TLEN  200
#define NP    30
#define HID   128
#define NSEQ  (BATCH * NP)   // 480
#define HXP   136            // h row pitch in halves (272 B -> 4-bank rotation/row)
#define XBP   72             // x-tile row pitch in halves (144 B)
#define XGW   520            // xgb row pitch in floats (2080 B -> 8-bank rotation/row)

typedef _Float16 half8 __attribute__((ext_vector_type(8)));
typedef float    f32x4 __attribute__((ext_vector_type(4)));

__device__ __forceinline__ float sigm_fast(float x) {
    return __builtin_amdgcn_rcpf(1.0f + __expf(-x));
}
__device__ __forceinline__ float tanh_fast(float x) {
    float xc = fminf(15.0f, fmaxf(-15.0f, x));
    float e = __expf(2.0f * xc);
    return (e - 1.0f) * __builtin_amdgcn_rcpf(e + 1.0f);
}
__device__ __forceinline__ half8 cvt8(float4 a, float4 b) {
    return (half8){(_Float16)a.x,(_Float16)a.y,(_Float16)a.z,(_Float16)a.w,
                   (_Float16)b.x,(_Float16)b.y,(_Float16)b.z,(_Float16)b.w};
}

#define MFMA16(A,B,C) __builtin_amdgcn_mfma_f32_16x16x32_f16((A),(B),(C),0,0,0)

// ---------------------------------------------------------------------------
// Fused LSTM. 240 blocks (XCD-swizzled), 512 threads = 8 waves = 2 waves/SIMD
// (1 wave/SIMD cannot saturate the MFMA pipe - r4 evidence). Wave w owns gate
// cols {128T + 16w + lr}: 16 MFMAs/wave/step, pipe-saturating at 2 waves/SIMD.
// Serial step path minimized:
//   - xg (x@W_ih + biases) precomputed per 8-step period, stored as f32 in
//     C-fragment layout -> per-step C-init is ONE float4 LDS read splatted
//     into the accumulators (rows 1-3 dead). No per-step adds/cvts/zero-init.
//   - A rows {0,4} = h_{s0},h_{s1}: C reg 0 of lane (lr,lq) IS cell
//     (hid=16w+lr, seq=lq) -> act on lanes<32, no selects, 1 ds_write each.
//   - x staged 2 periods ahead by lanes 32..47 (1 load + 1 LDS write/step).
//   - s_setprio(1) around the MFMA cluster (2 waves/SIMD role diversity).
// ---------------------------------------------------------------------------
__global__ __launch_bounds__(512, 2) void fused_lstm(
    const float* __restrict__ x, const float* __restrict__ W_ih,
    const float* __restrict__ W_hh, const float* __restrict__ b_ih,
    const float* __restrict__ b_hh, const float* __restrict__ W_fc,
    const float* __restrict__ b_fc, float* __restrict__ out)
{
    const int tid = threadIdx.x;
    const int w  = tid >> 6;     // wave 0..7 -> owns gate sub-cols 16w+lr
    const int l  = tid & 63;
    const int lr = l & 15;
    const int lq = l >> 4;

    // XCD-chunked swizzle: XCD c gets pairs c*30..c*30+29 (= 2 full batches)
    const int blk  = blockIdx.x;
    const int pair = (blk & 7) * 30 + (blk >> 3);
    const int n0 = pair * 2;
    const int b0 = n0 / NP;
    const int p0 = n0 % NP;      // even -> both seqs share b0

    __shared__ __align__(16) _Float16 hx2[2][16][HXP];   // h: row0=s0, row4=s1, rest 0
    __shared__ __align__(16) _Float16 xbuf[2][16][XBP];  // x tiles, row = 2*delta + s
    __shared__ __align__(16) float    xgb[2][16 * XGW];  // xg+bias, f32 C-layout:
                                                         // [buf][(2d+s)*XGW + hid*4 + T]

    // ---- W fragments in registers (loaded once) ----
    half8 bhh[4][4];   // W_hh, gate-type T, K-frag kt (K=128)
    half8 bih[4][2];   // W_ih, gate-type T, K-frag j  (K=64)
    float biasx[4];
#pragma unroll
    for (int T = 0; T < 4; ++T) {
        const int g = 128*T + 16*w + lr;
        const float* rh = W_hh + (size_t)g * HID;
        const float* ri = W_ih + (size_t)g * CH;
#pragma unroll
        for (int kt = 0; kt < 4; ++kt) {
            const int k0 = 32*kt + 8*lq;
            bhh[T][kt] = cvt8(*(const float4*)(rh + k0), *(const float4*)(rh + k0 + 4));
        }
#pragma unroll
        for (int j = 0; j < 2; ++j) {
            const int k0 = 32*j + 8*lq;
            bih[T][j] = cvt8(*(const float4*)(ri + k0), *(const float4*)(ri + k0 + 4));
        }
        biasx[T] = b_ih[g] + b_hh[g];
    }

    // zero hx2 (rows 1-3,5-15 stay zero forever; rows 0,4 = h_0 = 0)
    for (int i = tid; i < (2*16*HXP)/2; i += 512) ((unsigned*)hx2)[i] = 0u;

    // ---- x loaders: lanes 32..47 of each wave = 128 threads, one (s,ch) each
    const bool isload = (l >= 32 && l < 48);
    int ls = 0, lc = 0;
    const float* xbase = nullptr;
    float xpend = 0.f;
    if (isload) {
        const int idx = w * 16 + (l - 32);
        ls = idx >> 6;                    // seq 0/1
        lc = idx & 63;                    // channel
        xbase = x + ((size_t)(b0 * CH + lc) * TLEN) * NP + p0 + ls;
#pragma unroll
        for (int u = 0; u < 16; ++u)      // prologue: periods 0 and 1
            xbuf[u >> 3][2*(u & 7) + ls][lc] = (_Float16)xbase[(size_t)u * NP];
        xpend = xbase[(size_t)16 * NP];   // preload t=16 (staged at t=0)
    }
    float cst = 0.f;                      // c-state: lanes l<32 own (hid=16w+lr, s=lq)
    const int hcol = 16*w + lr;
    __syncthreads();                      // hx2 zeroed + xbuf[0],xbuf[1] staged

    // per-period xg GEMM: x-tile (16 rows = 8 steps x 2 seqs, K=64), bias folded.
    // C row (4lq+r) = xrow 2*delta+s -> store f32 quad {T0..T3} at that row.
#define XG_BURST(SB, TB) {                                                        \
        const _Float16* xr_ = &xbuf[SB][lr][8*lq];                                \
        half8 xf0_ = *(const half8*)xr_;                                          \
        half8 xf1_ = *(const half8*)(xr_ + 32);                                   \
        f32x4 g0_ = {biasx[0], biasx[0], biasx[0], biasx[0]};                     \
        f32x4 g1_ = {biasx[1], biasx[1], biasx[1], biasx[1]};                     \
        f32x4 g2_ = {biasx[2], biasx[2], biasx[2], biasx[2]};                     \
        f32x4 g3_ = {biasx[3], biasx[3], biasx[3], biasx[3]};                     \
        g0_ = MFMA16(xf0_, bih[0][0], g0_); g0_ = MFMA16(xf1_, bih[0][1], g0_);   \
        g1_ = MFMA16(xf0_, bih[1][0], g1_); g1_ = MFMA16(xf1_, bih[1][1], g1_);   \
        g2_ = MFMA16(xf0_, bih[2][0], g2_); g2_ = MFMA16(xf1_, bih[2][1], g2_);   \
        g3_ = MFMA16(xf0_, bih[3][0], g3_); g3_ = MFMA16(xf1_, bih[3][1], g3_);   \
        _Pragma("unroll") for (int r_ = 0; r_ < 4; ++r_) {                        \
            float* dst_ = &xgb[TB][(4*lq + r_) * XGW + hcol * 4];                 \
            *(f32x4*)dst_ = (f32x4){g0_[r_], g1_[r_], g2_[r_], g3_[r_]};          \
        } }

    XG_BURST(0, 0)          // xg for period 0
    __syncthreads();

#pragma unroll 1
    for (int p = 0; p < 25; ++p) {
        const int pe = p & 1;
#pragma unroll
        for (int k = 0; k < 8; ++k) {
            const int cur = k & 1;       // t = 8p+k, t&1 = k&1
            const int nxt = cur ^ 1;
            // C-init: this lane's 4 gate xg values (f32, 2-way-broadcast b128).
            // Lanes lq>=2 read the lq&1 row (their C rows are dead anyway).
            f32x4 xg4 = *(const f32x4*)&xgb[pe][(2*k + (lq & 1)) * XGW + hcol * 4];
            // A fragments (h, K=128); rows !=0,4 are zero -> dead C rows
            const _Float16* hr = &hx2[cur][lr][8*lq];
            half8 a0 = *(const half8*)(hr);
            half8 a1 = *(const half8*)(hr + 32);
            half8 a2 = *(const half8*)(hr + 64);
            half8 a3 = *(const half8*)(hr + 96);
            // accumulators: reg 0 = this lane's xg; regs 1-3 dead (splat ok)
            f32x4 ci = xg4;
            f32x4 cf = __builtin_shufflevector(xg4, xg4, 1, 1, 1, 1);
            f32x4 cg = __builtin_shufflevector(xg4, xg4, 2, 2, 2, 2);
            f32x4 co = __builtin_shufflevector(xg4, xg4, 3, 3, 3, 3);
            __builtin_amdgcn_s_setprio(1);
            ci = MFMA16(a0, bhh[0][0], ci); cf = MFMA16(a0, bhh[1][0], cf);
            cg = MFMA16(a0, bhh[2][0], cg); co = MFMA16(a0, bhh[3][0], co);
            ci = MFMA16(a1, bhh[0][1], ci); cf = MFMA16(a1, bhh[1][1], cf);
            cg = MFMA16(a1, bhh[2][1], cg); co = MFMA16(a1, bhh[3][1], co);
            ci = MFMA16(a2, bhh[0][2], ci); cf = MFMA16(a2, bhh[1][2], cf);
            cg = MFMA16(a2, bhh[2][2], cg); co = MFMA16(a2, bhh[3][2], co);
            ci = MFMA16(a3, bhh[0][3], ci); cf = MFMA16(a3, bhh[1][3], cf);
            cg = MFMA16(a3, bhh[2][3], cg); co = MFMA16(a3, bhh[3][3], co);
            __builtin_amdgcn_s_setprio(0);
            if (k == 0 && p < 24) XG_BURST(pe ^ 1, pe ^ 1)   // xg for period p+1
            if (l < 32) {
                // C reg 0 = row 4lq: row0=s0 (lq=0), row4=s1 (lq=1) -> own cell
                cst = sigm_fast(cf[0]) * cst + sigm_fast(ci[0]) * tanh_fast(cg[0]);
                float hv = sigm_fast(co[0]) * tanh_fast(cst);
                hx2[nxt][4*lq][hcol] = (_Float16)hv;
            } else if (isload) {
                // stage x for period p+2: t = 8p+k+16 -> row 2k+s of xbuf[pe]
                xbuf[pe][2*k + ls][lc] = (_Float16)xpend;
                int tq = 8*p + k + 17;
                tq = tq > TLEN - 1 ? TLEN - 1 : tq;
                xpend = xbase[(size_t)tq * NP];
            }
            __syncthreads();
        }
    }

    // FC epilogue: h_200 in hx2[0], seq s at row 4*s (t=199 wrote nxt=0)
    if (tid < 2 * CH) {
        const int s = tid >> 6, ch = tid & 63;
        const float* wf = W_fc + (size_t)ch * HID;
        float acc = b_fc[ch];
#pragma unroll
        for (int j8 = 0; j8 < 16; ++j8) {
            half8 hv = *(const half8*)&hx2[0][4*s][8 * j8];
            float4 w0 = *(const float4*)(wf + 8 * j8);
            float4 w1 = *(const float4*)(wf + 8 * j8 + 4);
            acc += w0.x * (float)hv[0] + w0.y * (float)hv[1]
                 + w0.z * (float)hv[2] + w0.w * (float)hv[3]
                 + w1.x * (float)hv[4] + w1.y * (float)hv[5]
                 + w1.z * (float)hv[6] + w1.w * (float)hv[7];
        }
        out[(size_t)(n0 + s) * CH + ch] = acc;
    }
}

extern "C" void kernel_launch(void* const* d_in, const int* in_sizes, int n_in,
                              void* d_out, int out_size, void* d_ws, size_t ws_size,
                              hipStream_t stream) {
    (void)in_sizes; (void)n_in; (void)out_size; (void)d_ws; (void)ws_size;
    fused_lstm<<<NSEQ / 2, 512, 0, stream>>>(
        (const float*)d_in[0], (const float*)d_in[1], (const float*)d_in[2],
        (const float*)d_in[3], (const float*)d_in[4], (const float*)d_in[5],
        (const float*)d_in[6], (float*)d_out);
}

// Round 7
// 193.440 us; speedup vs baseline: 1.0343x; 1.0114x over previous
//
#include <hip/hip_runtime.h>

#define BATCH 16
#define CH    64
#define TLEN  200
#define NP    30
#define HID   128
#define NSEQ  (BATCH * NP)   // 480
#define HXP   136            // h row pitch in halves (272 B)
#define XBP   72             // x-tile row pitch in halves (144 B)
#define XGW   520            // xgb row pitch in floats (2080 B)

typedef _Float16 half8 __attribute__((ext_vector_type(8)));
typedef float    f32x4 __attribute__((ext_vector_type(4)));

// NaN/Inf-safe, clamp-free: exp->inf degrades gracefully through rcp.
__device__ __forceinline__ float sigm_fast(float x) {
    return __builtin_amdgcn_rcpf(1.0f + __expf(-x));
}
__device__ __forceinline__ float tanh_fast(float x) {
    return 1.0f - 2.0f * __builtin_amdgcn_rcpf(__expf(2.0f * x) + 1.0f);
}
__device__ __forceinline__ half8 cvt8(float4 a, float4 b) {
    return (half8){(_Float16)a.x,(_Float16)a.y,(_Float16)a.z,(_Float16)a.w,
                   (_Float16)b.x,(_Float16)b.y,(_Float16)b.z,(_Float16)b.w};
}

#define MFMA16(A,B,C) __builtin_amdgcn_mfma_f32_16x16x32_f16((A),(B),(C),0,0,0)

// ---------------------------------------------------------------------------
// Fused LSTM. 240 blocks (XCD-swizzled), 512 threads = 8 waves = 2 waves/SIMD.
// Wave w owns gate cols {128T + 16w + lr}. r6 change: overlap the activation
// with the MFMA issue window instead of serializing after it:
//   - accumulator-major MFMA chains; i,f,g finish EARLY, o-gate chain LAST ->
//     sigm(i),sigm(f),tanh(g),c-update execute in the o-chain's issue gaps
//     (VALU co-issues with the matrix pipe across the 2 waves/SIMD).
//   - act math UNMASKED (64 lanes): lanes lq>=2 write garbage h into hx2
//     rows 8/12, which only feed dead C rows 8/12 (A row m -> C row m only).
//     Removes the exec-mask region that blocked scheduling.
//   - clamp-free tanh/sigm shorten the post-MFMA serial tail to ~sigm(go),
//     tanh(c), mul, cvt, ds_write.
// ---------------------------------------------------------------------------
__global__ __launch_bounds__(512, 2) void fused_lstm(
    const float* __restrict__ x, const float* __restrict__ W_ih,
    const float* __restrict__ W_hh, const float* __restrict__ b_ih,
    const float* __restrict__ b_hh, const float* __restrict__ W_fc,
    const float* __restrict__ b_fc, float* __restrict__ out)
{
    const int tid = threadIdx.x;
    const int w  = tid >> 6;     // wave 0..7 -> owns gate sub-cols 16w+lr
    const int l  = tid & 63;
    const int lr = l & 15;
    const int lq = l >> 4;

    // XCD-chunked swizzle: XCD c gets pairs c*30..c*30+29 (= 2 full batches)
    const int blk  = blockIdx.x;
    const int pair = (blk & 7) * 30 + (blk >> 3);
    const int n0 = pair * 2;
    const int b0 = n0 / NP;
    const int p0 = n0 % NP;      // even -> both seqs share b0

    __shared__ __align__(16) _Float16 hx2[2][16][HXP];   // h: row0=s0, row4=s1; rows 8,12 garbage (dead)
    __shared__ __align__(16) _Float16 xbuf[2][16][XBP];  // x tiles, row = 2*delta + s
    __shared__ __align__(16) float    xgb[2][16 * XGW];  // xg+bias, f32 C-layout

    // ---- W fragments in registers (loaded once) ----
    half8 bhh[4][4];   // W_hh, gate-type T, K-frag kt (K=128)
    half8 bih[4][2];   // W_ih, gate-type T, K-frag j  (K=64)
    float biasx[4];
#pragma unroll
    for (int T = 0; T < 4; ++T) {
        const int g = 128*T + 16*w + lr;
        const float* rh = W_hh + (size_t)g * HID;
        const float* ri = W_ih + (size_t)g * CH;
#pragma unroll
        for (int kt = 0; kt < 4; ++kt) {
            const int k0 = 32*kt + 8*lq;
            bhh[T][kt] = cvt8(*(const float4*)(rh + k0), *(const float4*)(rh + k0 + 4));
        }
#pragma unroll
        for (int j = 0; j < 2; ++j) {
            const int k0 = 32*j + 8*lq;
            bih[T][j] = cvt8(*(const float4*)(ri + k0), *(const float4*)(ri + k0 + 4));
        }
        biasx[T] = b_ih[g] + b_hh[g];
    }

    // zero hx2 (rows 0,4 = h_0 = 0; other rows only feed dead C rows)
    for (int i = tid; i < (2*16*HXP)/2; i += 512) ((unsigned*)hx2)[i] = 0u;

    // ---- x loaders: lanes 32..47 of each wave = 128 threads, one (s,ch) each
    const bool isload = (l >= 32 && l < 48);
    int ls = 0, lc = 0;
    const float* xbase = nullptr;
    float xpend = 0.f;
    if (isload) {
        const int idx = w * 16 + (l - 32);
        ls = idx >> 6;                    // seq 0/1
        lc = idx & 63;                    // channel
        xbase = x + ((size_t)(b0 * CH + lc) * TLEN) * NP + p0 + ls;
#pragma unroll
        for (int u = 0; u < 16; ++u)      // prologue: periods 0 and 1
            xbuf[u >> 3][2*(u & 7) + ls][lc] = (_Float16)xbase[(size_t)u * NP];
        xpend = xbase[(size_t)16 * NP];   // preload t=16 (staged at t=0)
    }
    float cst = 0.f;                      // c-state: valid in lanes l<32 (garbage elsewhere, unused)
    const int hcol = 16*w + lr;
    __syncthreads();                      // hx2 zeroed + xbuf[0],xbuf[1] staged

    // per-period xg GEMM: x-tile (16 rows = 8 steps x 2 seqs, K=64), bias folded.
#define XG_BURST(SB, TB) {                                                        \
        const _Float16* xr_ = &xbuf[SB][lr][8*lq];                                \
        half8 xf0_ = *(const half8*)xr_;                                          \
        half8 xf1_ = *(const half8*)(xr_ + 32);                                   \
        f32x4 g0_ = {biasx[0], biasx[0], biasx[0], biasx[0]};                     \
        f32x4 g1_ = {biasx[1], biasx[1], biasx[1], biasx[1]};                     \
        f32x4 g2_ = {biasx[2], biasx[2], biasx[2], biasx[2]};                     \
        f32x4 g3_ = {biasx[3], biasx[3], biasx[3], biasx[3]};                     \
        g0_ = MFMA16(xf0_, bih[0][0], g0_); g0_ = MFMA16(xf1_, bih[0][1], g0_);   \
        g1_ = MFMA16(xf0_, bih[1][0], g1_); g1_ = MFMA16(xf1_, bih[1][1], g1_);   \
        g2_ = MFMA16(xf0_, bih[2][0], g2_); g2_ = MFMA16(xf1_, bih[2][1], g2_);   \
        g3_ = MFMA16(xf0_, bih[3][0], g3_); g3_ = MFMA16(xf1_, bih[3][1], g3_);   \
        _Pragma("unroll") for (int r_ = 0; r_ < 4; ++r_) {                        \
            float* dst_ = &xgb[TB][(4*lq + r_) * XGW + hcol * 4];                 \
            *(f32x4*)dst_ = (f32x4){g0_[r_], g1_[r_], g2_[r_], g3_[r_]};          \
        } }

    XG_BURST(0, 0)          // xg for period 0
    __syncthreads();

#pragma unroll 1
    for (int p = 0; p < 25; ++p) {
        const int pe = p & 1;
#pragma unroll
        for (int k = 0; k < 8; ++k) {
            const int cur = k & 1;       // t = 8p+k, t&1 = k&1
            const int nxt = cur ^ 1;
            // C-init: this lane's 4 gate xg values (f32, row-broadcast b128)
            f32x4 xg4 = *(const f32x4*)&xgb[pe][(2*k + (lq & 1)) * XGW + hcol * 4];
            // A fragments (h, K=128)
            const _Float16* hr = &hx2[cur][lr][8*lq];
            half8 a0 = *(const half8*)(hr);
            half8 a1 = *(const half8*)(hr + 32);
            half8 a2 = *(const half8*)(hr + 64);
            half8 a3 = *(const half8*)(hr + 96);
            // accumulators: reg 0 = this lane's xg; regs 1-3 dead (splat ok)
            f32x4 ci = xg4;
            f32x4 cf = __builtin_shufflevector(xg4, xg4, 1, 1, 1, 1);
            f32x4 cg = __builtin_shufflevector(xg4, xg4, 2, 2, 2, 2);
            f32x4 co = __builtin_shufflevector(xg4, xg4, 3, 3, 3, 3);
            __builtin_amdgcn_s_setprio(1);
            // acc-major chains: i,f,g complete EARLY
            ci = MFMA16(a0, bhh[0][0], ci); ci = MFMA16(a1, bhh[0][1], ci);
            ci = MFMA16(a2, bhh[0][2], ci); ci = MFMA16(a3, bhh[0][3], ci);
            cf = MFMA16(a0, bhh[1][0], cf); cf = MFMA16(a1, bhh[1][1], cf);
            cf = MFMA16(a2, bhh[1][2], cf); cf = MFMA16(a3, bhh[1][3], cf);
            cg = MFMA16(a0, bhh[2][0], cg); cg = MFMA16(a1, bhh[2][1], cg);
            cg = MFMA16(a2, bhh[2][2], cg); cg = MFMA16(a3, bhh[2][3], cg);
            // early act (UNMASKED; garbage in lanes lq>=2 is discarded by row mapping)
            float si = sigm_fast(ci[0]);
            float sf = sigm_fast(cf[0]);
            float tg = tanh_fast(cg[0]);
            float cnew = sf * cst + si * tg;
            // o-gate chain LAST
            co = MFMA16(a0, bhh[3][0], co); co = MFMA16(a1, bhh[3][1], co);
            co = MFMA16(a2, bhh[3][2], co); co = MFMA16(a3, bhh[3][3], co);
            __builtin_amdgcn_s_setprio(0);
            if (k == 0 && p < 24) XG_BURST(pe ^ 1, pe ^ 1)   // xg for period p+1
            if (isload) {
                // stage x for period p+2: t = 8p+k+16 -> row 2k+s of xbuf[pe]
                xbuf[pe][2*k + ls][lc] = (_Float16)xpend;
                int tq = 8*p + k + 17;
                tq = tq > TLEN - 1 ? TLEN - 1 : tq;
                xpend = xbase[(size_t)tq * NP];
            }
            // short serial tail: sigm(go) || tanh(c) -> mul -> cvt -> write
            float hv = sigm_fast(co[0]) * tanh_fast(cnew);
            cst = cnew;
            hx2[nxt][4*lq][hcol] = (_Float16)hv;   // lq>=2 -> rows 8/12 (dead)
            __syncthreads();
        }
    }

    // FC epilogue: h_200 in hx2[0], seq s at row 4*s (t=199 wrote nxt=0)
    if (tid < 2 * CH) {
        const int s = tid >> 6, ch = tid & 63;
        const float* wf = W_fc + (size_t)ch * HID;
        float acc = b_fc[ch];
#pragma unroll
        for (int j8 = 0; j8 < 16; ++j8) {
            half8 hv = *(const half8*)&hx2[0][4*s][8 * j8];
            float4 w0 = *(const float4*)(wf + 8 * j8);
            float4 w1 = *(const float4*)(wf + 8 * j8 + 4);
            acc += w0.x * (float)hv[0] + w0.y * (float)hv[1]
                 + w0.z * (float)hv[2] + w0.w * (float)hv[3]
                 + w1.x * (float)hv[4] + w1.y * (float)hv[5]
                 + w1.z * (float)hv[6] + w1.w * (float)hv[7];
        }
        out[(size_t)(n0 + s) * CH + ch] = acc;
    }
}

extern "C" void kernel_launch(void* const* d_in, const int* in_sizes, int n_in,
                              void* d_out, int out_size, void* d_ws, size_t ws_size,
                              hipStream_t stream) {
    (void)in_sizes; (void)n_in; (void)out_size; (void)d_ws; (void)ws_size;
    fused_lstm<<<NSEQ / 2, 512, 0, stream>>>(
        (const float*)d_in[0], (const float*)d_in[1], (const float*)d_in[2],
        (const float*)d_in[3], (const float*)d_in[4], (const float*)d_in[5],
        (const float*)d_in[6], (float*)d_out);
}

// Round 8
// 192.569 us; speedup vs baseline: 1.0390x; 1.0045x over previous
//
#include <hip/hip_runtime.h>

#define BATCH 16
#define CH    64
#define TLEN  200
#define NP    30
#define HID   128
#define NSEQ  (BATCH * NP)   // 480
#define HXP   136            // h row pitch in halves (272 B)
#define XP    72             // xlds per-seq row pitch in halves (144 B)
#define XGW   520            // xgb row pitch in floats (2080 B)

typedef _Float16 half8 __attribute__((ext_vector_type(8)));
typedef float    f32x4 __attribute__((ext_vector_type(4)));

// NaN/Inf-safe, clamp-free: exp->inf degrades gracefully through rcp.
__device__ __forceinline__ float sigm_fast(float x) {
    return __builtin_amdgcn_rcpf(1.0f + __expf(-x));
}
__device__ __forceinline__ float tanh_fast(float x) {
    return 1.0f - 2.0f * __builtin_amdgcn_rcpf(__expf(2.0f * x) + 1.0f);
}
__device__ __forceinline__ half8 cvt8(float4 a, float4 b) {
    return (half8){(_Float16)a.x,(_Float16)a.y,(_Float16)a.z,(_Float16)a.w,
                   (_Float16)b.x,(_Float16)b.y,(_Float16)b.z,(_Float16)b.w};
}

#define MFMA16(A,B,C) __builtin_amdgcn_mfma_f32_16x16x32_f16((A),(B),(C),0,0,0)

// ---------------------------------------------------------------------------
// Fused LSTM. 240 blocks (XCD-swizzled), 512 threads = 8 waves = 2 waves/SIMD.
// r8 key change: the ENTIRE x for the block's 2 sequences (51.2 KB f16) is
// staged into LDS in the prologue -> the 200-step recurrent loop contains
// ZERO VMEM instructions. Previous rounds issued a global x load every step;
// the compiler's mandatory `s_waitcnt vmcnt(0)` before each s_barrier made
// every one of the 200 barriers eat HBM/L2 latency (~the entire ~550cy/step
// stall bucket that r4/r5/r7 restructurings never moved).
//   - XG_BURST (per-8-step xg GEMM, bias folded in C) reads x-tile rows
//     directly from resident xlds.
//   - xg applied act-side (4 adds) so its LDS read doesn't gate MFMA start;
//     accumulators zero-init.
//   - acc-major MFMA chains, o-gate last; act partials overlap the o-chain.
// ---------------------------------------------------------------------------
__global__ __launch_bounds__(512, 2) void fused_lstm(
    const float* __restrict__ x, const float* __restrict__ W_ih,
    const float* __restrict__ W_hh, const float* __restrict__ b_ih,
    const float* __restrict__ b_hh, const float* __restrict__ W_fc,
    const float* __restrict__ b_fc, float* __restrict__ out)
{
    const int tid = threadIdx.x;
    const int w  = tid >> 6;     // wave 0..7 -> owns gate sub-cols 16w+lr
    const int l  = tid & 63;
    const int lr = l & 15;
    const int lq = l >> 4;

    // XCD-chunked swizzle: XCD c gets pairs c*30..c*30+29 (= 2 full batches)
    const int blk  = blockIdx.x;
    const int pair = (blk & 7) * 30 + (blk >> 3);
    const int n0 = pair * 2;
    const int b0 = n0 / NP;
    const int p0 = n0 % NP;      // even -> both seqs share b0

    __shared__ __align__(16) _Float16 hx2[2][16][HXP];   // 8704 B; row0=s0,row4=s1; 8/12 garbage (dead)
    __shared__ __align__(16) _Float16 xlds[TLEN][2][XP]; // 57600 B; ALL x for both seqs, f16
    __shared__ __align__(16) float    xgb[2][16 * XGW];  // 66560 B; xg+bias, f32 C-layout

    // ---- W fragments in registers (loaded once) ----
    half8 bhh[4][4];   // W_hh, gate-type T, K-frag kt (K=128)
    half8 bih[4][2];   // W_ih, gate-type T, K-frag j  (K=64)
    float biasx[4];
#pragma unroll
    for (int T = 0; T < 4; ++T) {
        const int g = 128*T + 16*w + lr;
        const float* rh = W_hh + (size_t)g * HID;
        const float* ri = W_ih + (size_t)g * CH;
#pragma unroll
        for (int kt = 0; kt < 4; ++kt) {
            const int k0 = 32*kt + 8*lq;
            bhh[T][kt] = cvt8(*(const float4*)(rh + k0), *(const float4*)(rh + k0 + 4));
        }
#pragma unroll
        for (int j = 0; j < 2; ++j) {
            const int k0 = 32*j + 8*lq;
            bih[T][j] = cvt8(*(const float4*)(ri + k0), *(const float4*)(ri + k0 + 4));
        }
        biasx[T] = b_ih[g] + b_hh[g];
    }

    // zero hx2 (rows 0,4 = h_0 = 0; other rows only feed dead C rows)
    for (int i = tid; i < (2*16*HXP)/2; i += 512) ((unsigned*)hx2)[i] = 0u;

    // ---- prologue: stage ALL x for both seqs into LDS (one-time gather).
    // p0,p0+1 are adjacent floats -> one float2 per (c,t). 25 loads/thread.
    for (int e = tid; e < CH * TLEN; e += 512) {
        const int t = e % TLEN, c = e / TLEN;
        const float* src = x + ((size_t)(b0 * CH + c) * TLEN + t) * NP + p0;
        float2 v = *(const float2*)src;
        xlds[t][0][c] = (_Float16)v.x;
        xlds[t][1][c] = (_Float16)v.y;
    }
    float cst = 0.f;                      // c-state: valid in lanes l<32 (garbage elsewhere, unused)
    const int hcol = 16*w + lr;
    __syncthreads();                      // hx2 + xlds resident

    // per-period xg GEMM from resident xlds (rows t=8P..8P+7, both seqs).
    // A row lr -> (t = 8P + (lr>>1), seq = lr&1); C row (4lq+r) -> x-row 2δ+s.
#define XG_BURST(P, TB) {                                                         \
        const _Float16* xr_ = &xlds[8*(P) + (lr >> 1)][lr & 1][8*lq];             \
        half8 xf0_ = *(const half8*)xr_;                                          \
        half8 xf1_ = *(const half8*)(xr_ + 32);                                   \
        f32x4 g0_ = {biasx[0], biasx[0], biasx[0], biasx[0]};                     \
        f32x4 g1_ = {biasx[1], biasx[1], biasx[1], biasx[1]};                     \
        f32x4 g2_ = {biasx[2], biasx[2], biasx[2], biasx[2]};                     \
        f32x4 g3_ = {biasx[3], biasx[3], biasx[3], biasx[3]};                     \
        g0_ = MFMA16(xf0_, bih[0][0], g0_); g0_ = MFMA16(xf1_, bih[0][1], g0_);   \
        g1_ = MFMA16(xf0_, bih[1][0], g1_); g1_ = MFMA16(xf1_, bih[1][1], g1_);   \
        g2_ = MFMA16(xf0_, bih[2][0], g2_); g2_ = MFMA16(xf1_, bih[2][1], g2_);   \
        g3_ = MFMA16(xf0_, bih[3][0], g3_); g3_ = MFMA16(xf1_, bih[3][1], g3_);   \
        _Pragma("unroll") for (int r_ = 0; r_ < 4; ++r_) {                        \
            float* dst_ = &xgb[TB][(4*lq + r_) * XGW + hcol * 4];                 \
            *(f32x4*)dst_ = (f32x4){g0_[r_], g1_[r_], g2_[r_], g3_[r_]};          \
        } }

    XG_BURST(0, 0)          // xg for period 0
    __syncthreads();

#pragma unroll 1
    for (int p = 0; p < 25; ++p) {
        const int pe = p & 1;
#pragma unroll
        for (int k = 0; k < 8; ++k) {
            const int cur = k & 1;       // t = 8p+k, t&1 = k&1
            const int nxt = cur ^ 1;
            // xg read issued early, consumed act-side (doesn't gate MFMA start)
            f32x4 xg4 = *(const f32x4*)&xgb[pe][(2*k + (lq & 1)) * XGW + hcol * 4];
            // A fragments (h, K=128)
            const _Float16* hr = &hx2[cur][lr][8*lq];
            half8 a0 = *(const half8*)(hr);
            half8 a1 = *(const half8*)(hr + 32);
            half8 a2 = *(const half8*)(hr + 64);
            half8 a3 = *(const half8*)(hr + 96);
            f32x4 zz = {0.f, 0.f, 0.f, 0.f};
            f32x4 ci = zz, cf = zz, cg = zz, co = zz;
            __builtin_amdgcn_s_setprio(1);
            // acc-major chains: i,f,g complete EARLY
            ci = MFMA16(a0, bhh[0][0], ci); ci = MFMA16(a1, bhh[0][1], ci);
            ci = MFMA16(a2, bhh[0][2], ci); ci = MFMA16(a3, bhh[0][3], ci);
            cf = MFMA16(a0, bhh[1][0], cf); cf = MFMA16(a1, bhh[1][1], cf);
            cf = MFMA16(a2, bhh[1][2], cf); cf = MFMA16(a3, bhh[1][3], cf);
            cg = MFMA16(a0, bhh[2][0], cg); cg = MFMA16(a1, bhh[2][1], cg);
            cg = MFMA16(a2, bhh[2][2], cg); cg = MFMA16(a3, bhh[2][3], cg);
            // early act (UNMASKED; lanes lq>=2 produce garbage into dead rows)
            float si = sigm_fast(ci[0] + xg4[0]);
            float sf = sigm_fast(cf[0] + xg4[1]);
            float tg = tanh_fast(cg[0] + xg4[2]);
            float cnew = sf * cst + si * tg;
            // o-gate chain LAST
            co = MFMA16(a0, bhh[3][0], co); co = MFMA16(a1, bhh[3][1], co);
            co = MFMA16(a2, bhh[3][2], co); co = MFMA16(a3, bhh[3][3], co);
            __builtin_amdgcn_s_setprio(0);
            if (k == 0 && p < 24) XG_BURST(p + 1, pe ^ 1)    // xg for period p+1
            // short serial tail: sigm(go) || tanh(c) -> mul -> cvt -> write
            float hv = sigm_fast(co[0] + xg4[3]) * tanh_fast(cnew);
            cst = cnew;
            hx2[nxt][4*lq][hcol] = (_Float16)hv;   // lq>=2 -> rows 8/12 (dead)
            __syncthreads();
        }
    }

    // FC epilogue: h_200 in hx2[0], seq s at row 4*s (t=199 wrote nxt=0)
    if (tid < 2 * CH) {
        const int s = tid >> 6, ch = tid & 63;
        const float* wf = W_fc + (size_t)ch * HID;
        float acc = b_fc[ch];
#pragma unroll
        for (int j8 = 0; j8 < 16; ++j8) {
            half8 hv = *(const half8*)&hx2[0][4*s][8 * j8];
            float4 w0 = *(const float4*)(wf + 8 * j8);
            float4 w1 = *(const float4*)(wf + 8 * j8 + 4);
            acc += w0.x * (float)hv[0] + w0.y * (float)hv[1]
                 + w0.z * (float)hv[2] + w0.w * (float)hv[3]
                 + w1.x * (float)hv[4] + w1.y * (float)hv[5]
                 + w1.z * (float)hv[6] + w1.w * (float)hv[7];
        }
        out[(size_t)(n0 + s) * CH + ch] = acc;
    }
}

extern "C" void kernel_launch(void* const* d_in, const int* in_sizes, int n_in,
                              void* d_out, int out_size, void* d_ws, size_t ws_size,
                              hipStream_t stream) {
    (void)in_sizes; (void)n_in; (void)out_size; (void)d_ws; (void)ws_size;
    fused_lstm<<<NSEQ / 2, 512, 0, stream>>>(
        (const float*)d_in[0], (const float*)d_in[1], (const float*)d_in[2],
        (const float*)d_in[3], (const float*)d_in[4], (const float*)d_in[5],
        (const float*)d_in[6], (float*)d_out);
}

// Round 9
// 185.416 us; speedup vs baseline: 1.0790x; 1.0386x over previous
//
#include <hip/hip_runtime.h>

#define BATCH 16
#define CH    64
#define TLEN  200
#define NP    30
#define HID   128
#define NSEQ  (BATCH * NP)   // 480
#define HP    144            // hz row pitch in halves (288 B -> bank shift 8/row)
#define XP    72             // xlds per-seq row pitch in halves (144 B)
#define XGW   520            // xgb row pitch in floats (2080 B)

typedef _Float16 half8 __attribute__((ext_vector_type(8)));
typedef float    f32x4 __attribute__((ext_vector_type(4)));

// NaN/Inf-safe, clamp-free: exp->inf degrades gracefully through rcp.
__device__ __forceinline__ float sigm_fast(float x) {
    return __builtin_amdgcn_rcpf(1.0f + __expf(-x));
}
__device__ __forceinline__ float tanh_fast(float x) {
    return 1.0f - 2.0f * __builtin_amdgcn_rcpf(__expf(2.0f * x) + 1.0f);
}
__device__ __forceinline__ half8 cvt8(float4 a, float4 b) {
    return (half8){(_Float16)a.x,(_Float16)a.y,(_Float16)a.z,(_Float16)a.w,
                   (_Float16)b.x,(_Float16)b.y,(_Float16)b.z,(_Float16)b.w};
}

#define MFMA16(A,B,C) __builtin_amdgcn_mfma_f32_16x16x32_f16((A),(B),(C),0,0,0)

// ---------------------------------------------------------------------------
// Fused LSTM. 240 blocks (XCD-swizzled), 512 threads = 8 waves = 2 waves/SIMD.
// r9 key change: the A-tile LDS traffic is cut ~50x. Previous rounds stored h
// in a 16-row tile (14 rows zero) and every wave read the FULL tile per step:
// 32 ds_read_b128/CU-step ~ 500-600 cyc on the per-CU LDS pipe — a second
// bottleneck equal to the 620-cyc MFMA floor (the ~1600cy/step plateau of
// r3-r8 = imperfect overlap of those two + act tail).
// Now h is stored compactly: hz rows {0,1}=buf0 s0/s1, {2,3}=buf1, {4}=ZERO.
// Lane lr=0 reads the s0 row, lr=4 the s1 row, all other 14 lr values read
// the SHARED zero row (same address per lq-group -> broadcast, ~no bank
// traffic). A-read cost: ~60 cyc/CU-step. h-write: 32 masked b16.
//   - x fully resident in LDS (r8); zero VMEM in the loop.
//   - xg per-8-step burst GEMM (bias folded), f32 C-layout in xgb.
//   - acc-major MFMA chains, o-gate last; act front overlaps the o-chain.
// ---------------------------------------------------------------------------
__global__ __launch_bounds__(512, 2) void fused_lstm(
    const float* __restrict__ x, const float* __restrict__ W_ih,
    const float* __restrict__ W_hh, const float* __restrict__ b_ih,
    const float* __restrict__ b_hh, const float* __restrict__ W_fc,
    const float* __restrict__ b_fc, float* __restrict__ out)
{
    const int tid = threadIdx.x;
    const int w  = tid >> 6;     // wave 0..7 -> owns gate sub-cols 16w+lr
    const int l  = tid & 63;
    const int lr = l & 15;
    const int lq = l >> 4;

    // XCD-chunked swizzle: XCD c gets pairs c*30..c*30+29 (= 2 full batches)
    const int blk  = blockIdx.x;
    const int pair = (blk & 7) * 30 + (blk >> 3);
    const int n0 = pair * 2;
    const int b0 = n0 / NP;
    const int p0 = n0 % NP;      // even -> both seqs share b0

    __shared__ __align__(16) _Float16 hz[5][HP];         // 1440 B; h compact + zero row
    __shared__ __align__(16) _Float16 xlds[TLEN][2][XP]; // 57600 B; ALL x, f16
    __shared__ __align__(16) float    xgb[2][16 * XGW];  // 66560 B; xg+bias, f32 C-layout

    // ---- W fragments in registers (loaded once) ----
    half8 bhh[4][4];   // W_hh, gate-type T, K-frag kt (K=128)
    half8 bih[4][2];   // W_ih, gate-type T, K-frag j  (K=64)
    float biasx[4];
#pragma unroll
    for (int T = 0; T < 4; ++T) {
        const int g = 128*T + 16*w + lr;
        const float* rh = W_hh + (size_t)g * HID;
        const float* ri = W_ih + (size_t)g * CH;
#pragma unroll
        for (int kt = 0; kt < 4; ++kt) {
            const int k0 = 32*kt + 8*lq;
            bhh[T][kt] = cvt8(*(const float4*)(rh + k0), *(const float4*)(rh + k0 + 4));
        }
#pragma unroll
        for (int j = 0; j < 2; ++j) {
            const int k0 = 32*j + 8*lq;
            bih[T][j] = cvt8(*(const float4*)(ri + k0), *(const float4*)(ri + k0 + 4));
        }
        biasx[T] = b_ih[g] + b_hh[g];
    }

    // zero hz: rows 0-3 = h_0 = 0; row 4 = permanent zero row (never written)
    if (tid < (5 * HP) / 2) ((unsigned*)hz)[tid] = 0u;

    // ---- prologue: stage ALL x for both seqs into LDS (one-time gather).
    // p0,p0+1 are adjacent floats -> one float2 per (c,t). 25 loads/thread.
    for (int e = tid; e < CH * TLEN; e += 512) {
        const int t = e % TLEN, c = e / TLEN;
        const float* src = x + ((size_t)(b0 * CH + c) * TLEN + t) * NP + p0;
        float2 v = *(const float2*)src;
        xlds[t][0][c] = (_Float16)v.x;
        xlds[t][1][c] = (_Float16)v.y;
    }
    float cst = 0.f;                      // c-state: valid in lanes l<32
    const int hcol = 16*w + lr;
    // A-frag source rows: lr==0 -> seq0 row, lr==4 -> seq1 row, else ZERO row.
    const int hrow0 = (lr == 0) ? 0 : (lr == 4) ? 1 : 4;   // buf 0
    const int hrow1 = (lr == 0) ? 2 : (lr == 4) ? 3 : 4;   // buf 1
    const _Float16* hpA = &hz[hrow0][8 * lq];
    const _Float16* hpB = &hz[hrow1][8 * lq];
    __syncthreads();                      // hz + xlds resident

    // per-period xg GEMM from resident xlds (rows t=8P..8P+7, both seqs).
    // A row lr -> (t = 8P + (lr>>1), seq = lr&1); C row (4lq+r) -> x-row 2δ+s.
#define XG_BURST(P, TB) {                                                         \
        const _Float16* xr_ = &xlds[8*(P) + (lr >> 1)][lr & 1][8*lq];             \
        half8 xf0_ = *(const half8*)xr_;                                          \
        half8 xf1_ = *(const half8*)(xr_ + 32);                                   \
        f32x4 g0_ = {biasx[0], biasx[0], biasx[0], biasx[0]};                     \
        f32x4 g1_ = {biasx[1], biasx[1], biasx[1], biasx[1]};                     \
        f32x4 g2_ = {biasx[2], biasx[2], biasx[2], biasx[2]};                     \
        f32x4 g3_ = {biasx[3], biasx[3], biasx[3], biasx[3]};                     \
        g0_ = MFMA16(xf0_, bih[0][0], g0_); g0_ = MFMA16(xf1_, bih[0][1], g0_);   \
        g1_ = MFMA16(xf0_, bih[1][0], g1_); g1_ = MFMA16(xf1_, bih[1][1], g1_);   \
        g2_ = MFMA16(xf0_, bih[2][0], g2_); g2_ = MFMA16(xf1_, bih[2][1], g2_);   \
        g3_ = MFMA16(xf0_, bih[3][0], g3_); g3_ = MFMA16(xf1_, bih[3][1], g3_);   \
        _Pragma("unroll") for (int r_ = 0; r_ < 4; ++r_) {                        \
            float* dst_ = &xgb[TB][(4*lq + r_) * XGW + hcol * 4];                 \
            *(f32x4*)dst_ = (f32x4){g0_[r_], g1_[r_], g2_[r_], g3_[r_]};          \
        } }

    XG_BURST(0, 0)          // xg for period 0
    __syncthreads();

#pragma unroll 1
    for (int p = 0; p < 25; ++p) {
        const int pe = p & 1;
#pragma unroll
        for (int k = 0; k < 8; ++k) {
            const int cur = k & 1;       // t = 8p+k, t&1 = k&1
            const int nxt = cur ^ 1;
            // xg read issued early, consumed act-side (doesn't gate MFMA start)
            f32x4 xg4 = *(const f32x4*)&xgb[pe][(2*k + (lq & 1)) * XGW + hcol * 4];
            // A fragments: lanes lr in {0,4} read real h rows; 14/16 lane
            // groups broadcast-read the zero row -> ~no LDS bank traffic.
            const _Float16* hr = cur ? hpB : hpA;
            half8 a0 = *(const half8*)(hr);
            half8 a1 = *(const half8*)(hr + 32);
            half8 a2 = *(const half8*)(hr + 64);
            half8 a3 = *(const half8*)(hr + 96);
            f32x4 zz = {0.f, 0.f, 0.f, 0.f};
            f32x4 ci = zz, cf = zz, cg = zz, co = zz;
            __builtin_amdgcn_s_setprio(1);
            // acc-major chains: i,f,g complete EARLY
            ci = MFMA16(a0, bhh[0][0], ci); ci = MFMA16(a1, bhh[0][1], ci);
            ci = MFMA16(a2, bhh[0][2], ci); ci = MFMA16(a3, bhh[0][3], ci);
            cf = MFMA16(a0, bhh[1][0], cf); cf = MFMA16(a1, bhh[1][1], cf);
            cf = MFMA16(a2, bhh[1][2], cf); cf = MFMA16(a3, bhh[1][3], cf);
            cg = MFMA16(a0, bhh[2][0], cg); cg = MFMA16(a1, bhh[2][1], cg);
            cg = MFMA16(a2, bhh[2][2], cg); cg = MFMA16(a3, bhh[2][3], cg);
            // early act (all lanes; lanes l>=32 produce garbage, write masked)
            float si = sigm_fast(ci[0] + xg4[0]);
            float sf = sigm_fast(cf[0] + xg4[1]);
            float tg = tanh_fast(cg[0] + xg4[2]);
            float cnew = sf * cst + si * tg;
            // o-gate chain LAST
            co = MFMA16(a0, bhh[3][0], co); co = MFMA16(a1, bhh[3][1], co);
            co = MFMA16(a2, bhh[3][2], co); co = MFMA16(a3, bhh[3][3], co);
            __builtin_amdgcn_s_setprio(0);
            if (k == 0 && p < 24) XG_BURST(p + 1, pe ^ 1)    // xg for period p+1
            // short serial tail: sigm(go) || tanh(c) -> mul -> cvt -> write
            float hv = sigm_fast(co[0] + xg4[3]) * tanh_fast(cnew);
            cst = cnew;
            if (l < 32) hz[2*nxt + lq][hcol] = (_Float16)hv;  // compact h write
            __syncthreads();
        }
    }

    // FC epilogue: h_200 in hz rows 0,1 (t=199 wrote nxt=0)
    if (tid < 2 * CH) {
        const int s = tid >> 6, ch = tid & 63;
        const float* wf = W_fc + (size_t)ch * HID;
        float acc = b_fc[ch];
#pragma unroll
        for (int j8 = 0; j8 < 16; ++j8) {
            half8 hv = *(const half8*)&hz[s][8 * j8];
            float4 w0 = *(const float4*)(wf + 8 * j8);
            float4 w1 = *(const float4*)(wf + 8 * j8 + 4);
            acc += w0.x * (float)hv[0] + w0.y * (float)hv[1]
                 + w0.z * (float)hv[2] + w0.w * (float)hv[3]
                 + w1.x * (float)hv[4] + w1.y * (float)hv[5]
                 + w1.z * (float)hv[6] + w1.w * (float)hv[7];
        }
        out[(size_t)(n0 + s) * CH + ch] = acc;
    }
}

extern "C" void kernel_launch(void* const* d_in, const int* in_sizes, int n_in,
                              void* d_out, int out_size, void* d_ws, size_t ws_size,
                              hipStream_t stream) {
    (void)in_sizes; (void)n_in; (void)out_size; (void)d_ws; (void)ws_size;
    fused_lstm<<<NSEQ / 2, 512, 0, stream>>>(
        (const float*)d_in[0], (const float*)d_in[1], (const float*)d_in[2],
        (const float*)d_in[3], (const float*)d_in[4], (const float*)d_in[5],
        (const float*)d_in[6], (float*)d_out);
}